// Round 8
// baseline (70.753 us; speedup 1.0000x reference)
//
#include <hip/hip_runtime.h>

#define KINST 64

__device__ __forceinline__ int decode_k0(float t0, float t1, float t2,
                                         const int* pal_s) {
  int pid = (int)(fmaf(t0, 65536.f, fmaf(t1, 256.f, t2)) + 0.5f);
  if (pid >= 0 && pid < KINST && pal_s[pid] == pid) return pid;  // fast path
  for (int j = 0; j < KINST; ++j)
    if (pal_s[j] == pid) return j;
  return KINST;  // no palette match
}

// ---------------------------------------------------------------------------
// Pass 1: per-(b,block) PARTIAL histograms via LDS atomics; plain coalesced
// stores (no global atomics). nbs=256 -> 1 quad/thread, 4 blocks/CU.
// partialS: [B][nbs][256], index i = c*64+k.
// ---------------------------------------------------------------------------
__global__ __launch_bounds__(256) void k_stats(const float* __restrict__ pred,
                                               const float* __restrict__ targ,
                                               const int* __restrict__ pal,
                                               float* __restrict__ partialS,
                                               unsigned char* __restrict__ k0c,
                                               int HW) {
  int b = blockIdx.y;
  __shared__ float ls[4][4][KINST];  // [wave][component][k]
  __shared__ int pal_s[KINST];
  for (int i = threadIdx.x; i < 4 * 4 * KINST; i += blockDim.x)
    (&ls[0][0][0])[i] = 0.f;
  for (int i = threadIdx.x; i < KINST; i += blockDim.x) pal_s[i] = pal[i];
  __syncthreads();
  int w = threadIdx.x >> 6;
  const float* tb = targ + (size_t)b * 3 * HW;
  const float* pb = pred + (size_t)b * 3 * HW;
  unsigned char* kb = k0c ? k0c + (size_t)b * HW : nullptr;
  int nq = HW >> 2;
  const float4* tb4 = (const float4*)tb;
  const float4* pb4 = (const float4*)pb;
  for (int q = blockIdx.x * blockDim.x + threadIdx.x; q < nq;
       q += gridDim.x * blockDim.x) {
    float4 t0 = tb4[q], t1 = tb4[q + nq], t2 = tb4[q + 2 * nq];
    float4 p0 = pb4[q], p1 = pb4[q + nq], p2 = pb4[q + 2 * nq];
    int ka = decode_k0(t0.x, t1.x, t2.x, pal_s);
    int kc = decode_k0(t0.y, t1.y, t2.y, pal_s);
    int kd = decode_k0(t0.z, t1.z, t2.z, pal_s);
    int ke = decode_k0(t0.w, t1.w, t2.w, pal_s);
    if (ka < KINST) {
      atomicAdd(&ls[w][0][ka], p0.x); atomicAdd(&ls[w][1][ka], p1.x);
      atomicAdd(&ls[w][2][ka], p2.x); atomicAdd(&ls[w][3][ka], 1.f);
    }
    if (kc < KINST) {
      atomicAdd(&ls[w][0][kc], p0.y); atomicAdd(&ls[w][1][kc], p1.y);
      atomicAdd(&ls[w][2][kc], p2.y); atomicAdd(&ls[w][3][kc], 1.f);
    }
    if (kd < KINST) {
      atomicAdd(&ls[w][0][kd], p0.z); atomicAdd(&ls[w][1][kd], p1.z);
      atomicAdd(&ls[w][2][kd], p2.z); atomicAdd(&ls[w][3][kd], 1.f);
    }
    if (ke < KINST) {
      atomicAdd(&ls[w][0][ke], p0.w); atomicAdd(&ls[w][1][ke], p1.w);
      atomicAdd(&ls[w][2][ke], p2.w); atomicAdd(&ls[w][3][ke], 1.f);
    }
    if (kb) {
      uchar4 kk = make_uchar4((unsigned char)ka, (unsigned char)kc,
                              (unsigned char)kd, (unsigned char)ke);
      *(uchar4*)(kb + 4 * (size_t)q) = kk;
    }
  }
  // scalar tail (HW % 4 != 0 only)
  for (int i = (nq << 2) + blockIdx.x * blockDim.x + threadIdx.x; i < HW;
       i += gridDim.x * blockDim.x) {
    int k0 = decode_k0(tb[i], tb[i + HW], tb[i + 2 * HW], pal_s);
    if (kb) kb[i] = (unsigned char)k0;
    if (k0 < KINST) {
      atomicAdd(&ls[w][0][k0], pb[i]); atomicAdd(&ls[w][1][k0], pb[i + HW]);
      atomicAdd(&ls[w][2][k0], pb[i + 2 * HW]); atomicAdd(&ls[w][3][k0], 1.f);
    }
  }
  __syncthreads();
  float* out = partialS + ((size_t)b * gridDim.x + blockIdx.x) * 256;
  int i = threadIdx.x;  // i = c*64+k
  int c = i >> 6, k = i & 63;
  out[i] = ls[0][c][k] + ls[1][c][k] + ls[2][c][k] + ls[3][c][k];
}

// ---------------------------------------------------------------------------
// Pass 2 (grid=B): reduce partials -> sums; build all per-(b,k) tables:
// A_g[b][65] = {-2m0,-2m1,-2m2,|m|^2+1}, W_g[b][65] = 300*dw0*scale,
// Z_g[b][65] = {mz0,mz1,mz2,f_intra}, cw_g[b][k*65+k0] (general-dw path),
// flagp[b] = dw non-uniformity.
// ---------------------------------------------------------------------------
__global__ __launch_bounds__(256) void k_reduce(const float* __restrict__ partialS,
                                                const float* __restrict__ dw,
                                                const int* __restrict__ pal,
                                                const unsigned char* __restrict__ nb_raw,
                                                int ndw, int nbs,
                                                float* __restrict__ sums,
                                                float4* __restrict__ A_g,
                                                float* __restrict__ W_g,
                                                float4* __restrict__ Z_g,
                                                float* __restrict__ cw_g,
                                                int* __restrict__ flagp,
                                                int B, int HW) {
  int b = blockIdx.x;
  int i = threadIdx.x;
  __shared__ float red[256];
  __shared__ float scale_sh[KINST];
  __shared__ int nu_sh;
  const float* src = partialS + (size_t)b * nbs * 256;
  float a0 = 0.f, a1 = 0.f, a2 = 0.f, a3 = 0.f;
  int bx = 0;
  #pragma unroll 4
  for (; bx + 4 <= nbs; bx += 4) {
    a0 += src[(size_t)(bx + 0) * 256 + i];
    a1 += src[(size_t)(bx + 1) * 256 + i];
    a2 += src[(size_t)(bx + 2) * 256 + i];
    a3 += src[(size_t)(bx + 3) * 256 + i];
  }
  for (; bx < nbs; ++bx) a0 += src[(size_t)bx * 256 + i];
  float acc = (a0 + a1) + (a2 + a3);
  red[i] = acc;
  int c = i >> 6, k = i & 63;
  sums[((size_t)b * KINST + k) * 4 + c] = acc;
  // dw-uniformity scan (chunked across the B blocks)
  if (i == 0) nu_sh = 0;
  __syncthreads();
  {
    int per = (ndw + B - 1) / B;
    int lo = b * per, hi = min(lo + per, ndw);
    float d0 = dw[0];
    int nu = 0;
    for (int x = lo + i; x < hi; x += blockDim.x) nu |= (dw[x] != d0);
    if (nu) atomicOr(&nu_sh, 1);
  }
  // per-k derived tables
  if (i < KINST) {
    float s0 = red[i], s1 = red[64 + i], s2 = red[128 + i], cnt = red[192 + i];
    float inv = cnt > 0.f ? 1.f / cnt : 0.f;
    float m0 = s0 * inv, m1 = s1 * inv, m2 = s2 * inv;
    bool isbg = (pal[i] == 0);
    bool nb = (nb_raw[b] != 0) || (nb_raw[4 * b] != 0);  // robust bool width
    float cf = (!isbg || !nb) ? 1.f : 0.f;
    float sc = (!isbg && cnt > 0.f) ? 10.f / (((float)HW - cnt) * sqrtf(cnt)) : 0.f;
    A_g[b * 65 + i] = make_float4(-2.f * m0, -2.f * m1, -2.f * m2,
                                  m0 * m0 + m1 * m1 + m2 * m2 + 1.f);
    Z_g[b * 65 + i] = make_float4(isbg ? 0.f : m0, isbg ? 0.f : m1,
                                  isbg ? 0.f : m2,
                                  cnt > 0.f ? cf / (3.f * cnt) : 0.f);
    W_g[b * 65 + i] = 300.f * dw[0] * sc;
    scale_sh[i] = sc;
  }
  if (i == KINST) {
    A_g[b * 65 + KINST] = make_float4(0.f, 0.f, 0.f, 1.f);
    Z_g[b * 65 + KINST] = make_float4(0.f, 0.f, 0.f, 0.f);
    W_g[b * 65 + KINST] = 0.f;
  }
  __syncthreads();
  if (i == 0) flagp[b] = nu_sh;
  // general-dw weight table (only consumed when dw is non-uniform)
  if (nu_sh) {
    float* ct = cw_g + (size_t)b * KINST * 65;
    for (int t2 = i; t2 < KINST * 65; t2 += blockDim.x) {
      int kk = t2 / 65, j = t2 - kk * 65;
      float v = 0.f;
      if (j < KINST && j != kk) v = 300.f * dw[kk * KINST + j] * scale_sh[kk];
      ct[t2] = v;
    }
  }
}

// ---------------------------------------------------------------------------
// Pass 3 (hot): pixel-per-lane, 4 px/thread. Per-k constants A/W read from
// GLOBAL with wave-uniform index -> scalar loads (s_load), freeing the LDS
// pipe. LDS keeps only per-pixel gather tables (Z, diag copies of A/W).
// res_part: [B][gridDim.x][2] = {intra, inter}, plain stores.
// ---------------------------------------------------------------------------
template <bool USE_CACHE>
__global__ __launch_bounds__(256) void k_pix(const float* __restrict__ pred,
                                             const float* __restrict__ targ,
                                             const unsigned char* __restrict__ k0c,
                                             const int* __restrict__ pal,
                                             const float4* __restrict__ A_g,
                                             const float* __restrict__ W_g,
                                             const float4* __restrict__ Z_g,
                                             const float* __restrict__ cw_g,
                                             const int* __restrict__ flagp,
                                             float* __restrict__ res_part,
                                             int HW, int B) {
  int b = blockIdx.y;
  __shared__ float4 Z_s[KINST + 1];
  __shared__ float4 A_sl[KINST + 1];  // for per-pixel diag gather
  __shared__ float W_sl[KINST + 1];
  __shared__ int pal_s[KINST];
  __shared__ int nonuni_s;
  __shared__ float rA[4], rB[4];
  int t = threadIdx.x;
  if (t < KINST + 1) {
    Z_s[t] = Z_g[b * 65 + t];
    A_sl[t] = A_g[b * 65 + t];
    W_sl[t] = W_g[b * 65 + t];
  }
  if (!USE_CACHE && t < KINST) pal_s[t] = pal[t];
  if (t == 0) {
    int f = 0;
    for (int bb = 0; bb < B; ++bb) f |= flagp[bb];
    nonuni_s = f;
  }
  __syncthreads();
  bool nonuni = nonuni_s != 0;
  const float4* pA = A_g + b * 65;   // uniform-index reads -> scalar loads
  const float* pW = W_g + b * 65;
  const float* cwb = cw_g + (size_t)b * KINST * 65;
  const float* pb = pred + (size_t)b * 3 * HW;
  const float* tb = targ + (size_t)b * 3 * HW;
  const float4* pb4 = (const float4*)pb;
  const float4* tb4 = (const float4*)tb;
  int nq = HW >> 2;
  const uchar4* kb4 = USE_CACHE ? (const uchar4*)(k0c + (size_t)b * HW) : nullptr;
  float intra_l = 0.f, inter_l = 0.f;
  for (int q = blockIdx.x * blockDim.x + t; q < nq;
       q += gridDim.x * blockDim.x) {
    float4 P0 = pb4[q], P1 = pb4[q + nq], P2 = pb4[q + 2 * nq];
    int ka, kc, kd, ke;
    if (USE_CACHE) {
      uchar4 kk = kb4[q];
      ka = kk.x; kc = kk.y; kd = kk.z; ke = kk.w;
    } else {
      float4 T0 = tb4[q], T1 = tb4[q + nq], T2 = tb4[q + 2 * nq];
      ka = decode_k0(T0.x, T1.x, T2.x, pal_s);
      kc = decode_k0(T0.y, T1.y, T2.y, pal_s);
      kd = decode_k0(T0.z, T1.z, T2.z, pal_s);
      ke = decode_k0(T0.w, T1.w, T2.w, pal_s);
    }
    float ppa = fmaf(P0.x, P0.x, fmaf(P1.x, P1.x, P2.x * P2.x));
    float ppb = fmaf(P0.y, P0.y, fmaf(P1.y, P1.y, P2.y * P2.y));
    float ppc = fmaf(P0.z, P0.z, fmaf(P1.z, P1.z, P2.z * P2.z));
    float ppd = fmaf(P0.w, P0.w, fmaf(P1.w, P1.w, P2.w * P2.w));
    float aa = 0.f, ab = 0.f, ac = 0.f, ad = 0.f;
    if (!nonuni) {
      #pragma unroll 8
      for (int k = 0; k < KINST; ++k) {
        float4 a = pA[k];   // wave-uniform -> s_load_dwordx4
        float wv = pW[k];   // wave-uniform -> s_load_dword
        float ra = __builtin_amdgcn_rcpf(
            ppa + fmaf(P0.x, a.x, fmaf(P1.x, a.y, fmaf(P2.x, a.z, a.w))));
        float rb = __builtin_amdgcn_rcpf(
            ppb + fmaf(P0.y, a.x, fmaf(P1.y, a.y, fmaf(P2.y, a.z, a.w))));
        float rc = __builtin_amdgcn_rcpf(
            ppc + fmaf(P0.z, a.x, fmaf(P1.z, a.y, fmaf(P2.z, a.z, a.w))));
        float rd = __builtin_amdgcn_rcpf(
            ppd + fmaf(P0.w, a.x, fmaf(P1.w, a.y, fmaf(P2.w, a.z, a.w))));
        aa = fmaf(ra, wv, aa); ab = fmaf(rb, wv, ab);
        ac = fmaf(rc, wv, ac); ad = fmaf(rd, wv, ad);
      }
      // diagonal (k==k0) subtract + invalid-pixel mask (LDS gathers)
      {
        float4 a = A_sl[ka]; float wv = W_sl[ka];
        float r = __builtin_amdgcn_rcpf(
            ppa + fmaf(P0.x, a.x, fmaf(P1.x, a.y, fmaf(P2.x, a.z, a.w))));
        aa = (ka < KINST) ? aa - wv * r : 0.f;
      }
      {
        float4 a = A_sl[kc]; float wv = W_sl[kc];
        float r = __builtin_amdgcn_rcpf(
            ppb + fmaf(P0.y, a.x, fmaf(P1.y, a.y, fmaf(P2.y, a.z, a.w))));
        ab = (kc < KINST) ? ab - wv * r : 0.f;
      }
      {
        float4 a = A_sl[kd]; float wv = W_sl[kd];
        float r = __builtin_amdgcn_rcpf(
            ppc + fmaf(P0.z, a.x, fmaf(P1.z, a.y, fmaf(P2.z, a.z, a.w))));
        ac = (kd < KINST) ? ac - wv * r : 0.f;
      }
      {
        float4 a = A_sl[ke]; float wv = W_sl[ke];
        float r = __builtin_amdgcn_rcpf(
            ppd + fmaf(P0.w, a.x, fmaf(P1.w, a.y, fmaf(P2.w, a.z, a.w))));
        ad = (ke < KINST) ? ad - wv * r : 0.f;
      }
    } else {
      #pragma unroll 4
      for (int k = 0; k < KINST; ++k) {
        float4 a = pA[k];
        float ra = __builtin_amdgcn_rcpf(
            ppa + fmaf(P0.x, a.x, fmaf(P1.x, a.y, fmaf(P2.x, a.z, a.w))));
        float rb = __builtin_amdgcn_rcpf(
            ppb + fmaf(P0.y, a.x, fmaf(P1.y, a.y, fmaf(P2.y, a.z, a.w))));
        float rc = __builtin_amdgcn_rcpf(
            ppc + fmaf(P0.z, a.x, fmaf(P1.z, a.y, fmaf(P2.z, a.z, a.w))));
        float rd = __builtin_amdgcn_rcpf(
            ppd + fmaf(P0.w, a.x, fmaf(P1.w, a.y, fmaf(P2.w, a.z, a.w))));
        // cw gather from global (L1-resident 16.6KB): diag/invalid -> 0
        aa = fmaf(ra, cwb[k * 65 + ka], aa); ab = fmaf(rb, cwb[k * 65 + kc], ab);
        ac = fmaf(rc, cwb[k * 65 + kd], ac); ad = fmaf(rd, cwb[k * 65 + ke], ad);
      }
    }
    inter_l += (aa + ab) + (ac + ad);
    // intra: huber toward own bg-zeroed mean; f_intra folds cf/(3*cnt)
    {
      float4 z = Z_s[ka];
      float q0 = fabsf(P0.x - z.x), q1 = fabsf(P1.x - z.y), q2 = fabsf(P2.x - z.z);
      float hp = (q0 < 1.f ? 0.5f * q0 * q0 : q0 - 0.5f) +
                 (q1 < 1.f ? 0.5f * q1 * q1 : q1 - 0.5f) +
                 (q2 < 1.f ? 0.5f * q2 * q2 : q2 - 0.5f);
      intra_l = fmaf(hp, z.w, intra_l);
    }
    {
      float4 z = Z_s[kc];
      float q0 = fabsf(P0.y - z.x), q1 = fabsf(P1.y - z.y), q2 = fabsf(P2.y - z.z);
      float hp = (q0 < 1.f ? 0.5f * q0 * q0 : q0 - 0.5f) +
                 (q1 < 1.f ? 0.5f * q1 * q1 : q1 - 0.5f) +
                 (q2 < 1.f ? 0.5f * q2 * q2 : q2 - 0.5f);
      intra_l = fmaf(hp, z.w, intra_l);
    }
    {
      float4 z = Z_s[kd];
      float q0 = fabsf(P0.z - z.x), q1 = fabsf(P1.z - z.y), q2 = fabsf(P2.z - z.z);
      float hp = (q0 < 1.f ? 0.5f * q0 * q0 : q0 - 0.5f) +
                 (q1 < 1.f ? 0.5f * q1 * q1 : q1 - 0.5f) +
                 (q2 < 1.f ? 0.5f * q2 * q2 : q2 - 0.5f);
      intra_l = fmaf(hp, z.w, intra_l);
    }
    {
      float4 z = Z_s[ke];
      float q0 = fabsf(P0.w - z.x), q1 = fabsf(P1.w - z.y), q2 = fabsf(P2.w - z.z);
      float hp = (q0 < 1.f ? 0.5f * q0 * q0 : q0 - 0.5f) +
                 (q1 < 1.f ? 0.5f * q1 * q1 : q1 - 0.5f) +
                 (q2 < 1.f ? 0.5f * q2 * q2 : q2 - 0.5f);
      intra_l = fmaf(hp, z.w, intra_l);
    }
  }
  // scalar tail pixels (HW % 4 != 0 only)
  for (int i = (nq << 2) + blockIdx.x * blockDim.x + t; i < HW;
       i += gridDim.x * blockDim.x) {
    float p0 = pb[i], p1 = pb[i + HW], p2 = pb[i + 2 * HW];
    int k0 = USE_CACHE ? (int)k0c[(size_t)b * HW + i]
                       : decode_k0(tb[i], tb[i + HW], tb[i + 2 * HW], pal_s);
    float pp = fmaf(p0, p0, fmaf(p1, p1, p2 * p2));
    float acc = 0.f;
    for (int k = 0; k < KINST; ++k) {
      float4 a = A_sl[k];
      float r = __builtin_amdgcn_rcpf(
          pp + fmaf(p0, a.x, fmaf(p1, a.y, fmaf(p2, a.z, a.w))));
      float c = nonuni ? cwb[k * 65 + k0]
                       : ((k == k0 || k0 >= KINST) ? 0.f : W_sl[k]);
      acc = fmaf(r, c, acc);
    }
    inter_l += acc;
    float4 z = Z_s[k0];
    float q0 = fabsf(p0 - z.x), q1 = fabsf(p1 - z.y), q2 = fabsf(p2 - z.z);
    float hp = (q0 < 1.f ? 0.5f * q0 * q0 : q0 - 0.5f) +
               (q1 < 1.f ? 0.5f * q1 * q1 : q1 - 0.5f) +
               (q2 < 1.f ? 0.5f * q2 * q2 : q2 - 0.5f);
    intra_l = fmaf(hp, z.w, intra_l);
  }
  for (int o = 32; o > 0; o >>= 1) {
    intra_l += __shfl_down(intra_l, o, 64);
    inter_l += __shfl_down(inter_l, o, 64);
  }
  int wid = threadIdx.x >> 6;
  if ((threadIdx.x & 63) == 0) { rA[wid] = intra_l; rB[wid] = inter_l; }
  __syncthreads();
  if (threadIdx.x == 0) {
    float a = 0.f, c = 0.f;
    for (int i = 0; i < 4; ++i) { a += rA[i]; c += rB[i]; }
    float* rp = res_part + ((size_t)b * gridDim.x + blockIdx.x) * 2;
    rp[0] = a; rp[1] = c;  // plain store, no atomics
  }
}

// ---------------------------------------------------------------------------
// Pass 4: single block; reduce res_part (fixed order), recompute means from
// sums, pairwise repulsion, final combine -> out[0].
// ---------------------------------------------------------------------------
__global__ __launch_bounds__(256) void k_final(const float* __restrict__ sums,
                                               const int* __restrict__ pal,
                                               const unsigned char* __restrict__ nb_raw,
                                               const float* __restrict__ dw,
                                               const float* __restrict__ res_part,
                                               int ngx,
                                               float* __restrict__ out,
                                               int B, int HW) {
  __shared__ float4 zf[KINST];  // {mz0,mz1,mz2, cf}
  __shared__ float rA[4], rB[4], rC[4], rD[4], rE[4];
  float total = 0.f;
  for (int b = 0; b < B; ++b) {
    __syncthreads();
    if (threadIdx.x < KINST) {
      int k = threadIdx.x;
      float4 s = ((const float4*)sums)[b * KINST + k];
      float cnt = s.w;
      float inv = cnt > 0.f ? 1.f / cnt : 0.f;
      bool isbg = (pal[k] == 0);
      bool nb = (nb_raw[b] != 0) || (nb_raw[4 * b] != 0);
      float cf = (!isbg || !nb) ? 1.f : 0.f;
      zf[k] = make_float4(isbg ? 0.f : s.x * inv, isbg ? 0.f : s.y * inv,
                          isbg ? 0.f : s.z * inv, cf);
    }
    __syncthreads();
    float psum = 0.f, pcnt = 0.f, cfs = 0.f, ra = 0.f, rc = 0.f;
    for (int idx = threadIdx.x; idx < KINST * KINST; idx += blockDim.x) {
      int j = idx >> 6, k = idx & 63;
      if (j < k) {
        float4 a = zf[j], c4 = zf[k];
        float m = a.w * c4.w;
        float d0 = a.x - c4.x, d1 = a.y - c4.y, d2 = a.z - c4.z;
        float sqd = d0 * d0 + d1 * d1 + d2 * d2;
        psum += dw[j * KINST + k] * 300.f / (sqd + 1.f) * m;
        pcnt += m;
      }
    }
    if (threadIdx.x < KINST) cfs = zf[threadIdx.x].w;
    for (int bx = threadIdx.x; bx < ngx; bx += blockDim.x) {
      const float* rp = res_part + ((size_t)b * ngx + bx) * 2;
      ra += rp[0]; rc += rp[1];
    }
    for (int o = 32; o > 0; o >>= 1) {
      psum += __shfl_down(psum, o, 64);
      pcnt += __shfl_down(pcnt, o, 64);
      cfs += __shfl_down(cfs, o, 64);
      ra += __shfl_down(ra, o, 64);
      rc += __shfl_down(rc, o, 64);
    }
    int wid = threadIdx.x >> 6;
    if ((threadIdx.x & 63) == 0) {
      rA[wid] = psum; rB[wid] = pcnt; rC[wid] = cfs; rD[wid] = ra; rE[wid] = rc;
    }
    __syncthreads();
    if (threadIdx.x == 0) {
      float ps = 0.f, pc = 0.f, cs = 0.f, sa = 0.f, sc2 = 0.f;
      for (int i = 0; i < 4; ++i) {
        ps += rA[i]; pc += rB[i]; cs += rC[i]; sa += rD[i]; sc2 += rE[i];
      }
      float mean_sep = pc > 0.f ? ps / fmaxf(pc, 1.f) : 0.f;
      float ct = fmaxf(cs, 1.f);
      total += (sa + sc2 + mean_sep) / ct;
    }
  }
  if (threadIdx.x == 0) out[0] = total / (float)B;
}

extern "C" void kernel_launch(void* const* d_in, const int* in_sizes, int n_in,
                              void* d_out, int out_size, void* d_ws, size_t ws_size,
                              hipStream_t stream) {
  const float* pred = (const float*)d_in[0];
  const float* targ = (const float*)d_in[1];
  const unsigned char* nb = (const unsigned char*)d_in[2];
  const float* dw = (const float*)d_in[3];
  const int* pal = (const int*)d_in[4];
  int B = in_sizes[2];                 // 4
  int ndw = in_sizes[3];               // K*K = 4096
  int HW = in_sizes[0] / (3 * B);      // 262144  (kernels assume K==64)
  const int GX = 256;                  // k_pix blocks per b

  // ws layout (floats):
  // partialS[B*nbs*256] | sums[B*256] | res_part[B*GX*2] | flagp[B]
  // | A_g[B*65*4] | W_g[B*65] | Z_g[B*65*4] | cw_g[B*64*65]
  // then bytes: k0c[B*HW] if it fits
  auto floats_needed = [&](int nbs) -> size_t {
    return (size_t)B * nbs * 256 + (size_t)B * 256 + (size_t)B * GX * 2 + B +
           (size_t)B * 65 * 4 + (size_t)B * 65 + (size_t)B * 65 * 4 +
           (size_t)B * KINST * 65;
  };
  int nbs = 256;
  bool use_cache = true;
  if (ws_size < floats_needed(256) * 4 + (size_t)B * HW) {
    if (ws_size >= floats_needed(32) * 4 + (size_t)B * HW) nbs = 32;
    else { nbs = 32; use_cache = false; }
  }
  float* partialS = (float*)d_ws;
  float* sums = partialS + (size_t)B * nbs * 256;
  float* res_part = sums + (size_t)B * 256;
  int* flagp = (int*)(res_part + (size_t)B * GX * 2);
  float4* A_g = (float4*)(flagp + B);
  float* W_g = (float*)(A_g + (size_t)B * 65);
  float4* Z_g = (float4*)(W_g + (size_t)B * 65);
  float* cw_g = (float*)(Z_g + (size_t)B * 65);
  unsigned char* k0c = use_cache ? (unsigned char*)(cw_g + (size_t)B * KINST * 65)
                                 : nullptr;

  k_stats<<<dim3(nbs, B), 256, 0, stream>>>(pred, targ, pal, partialS, k0c, HW);
  k_reduce<<<B, 256, 0, stream>>>(partialS, dw, pal, nb, ndw, nbs, sums, A_g,
                                  W_g, Z_g, cw_g, flagp, B, HW);
  if (use_cache)
    k_pix<true><<<dim3(GX, B), 256, 0, stream>>>(pred, targ, k0c, pal, A_g, W_g,
                                                 Z_g, cw_g, flagp, res_part, HW, B);
  else
    k_pix<false><<<dim3(GX, B), 256, 0, stream>>>(pred, targ, k0c, pal, A_g, W_g,
                                                  Z_g, cw_g, flagp, res_part, HW, B);
  k_final<<<1, 256, 0, stream>>>(sums, pal, nb, dw, res_part, GX,
                                 (float*)d_out, B, HW);
}